// Round 1
// baseline (1261.610 us; speedup 1.0000x reference)
//
#include <hip/hip_runtime.h>
#include <math.h>

#define NN 50000
#define NE 800000
#define INF 512
#define HID 64
#define OUTF 40
#define NL 16
#define PADN 65

// bf16 helpers: RNE pack, cheap unpack
__device__ __forceinline__ unsigned int f2bf(float f) {
    unsigned int u = __float_as_uint(f);
    return (u + 0x7fffu + ((u >> 16) & 1u)) >> 16;
}
__device__ __forceinline__ float bflo(unsigned int w) { return __uint_as_float(w << 16); }
__device__ __forceinline__ float bfhi(unsigned int w) { return __uint_as_float(w & 0xffff0000u); }

// ---------------- setup kernels ----------------

__global__ __launch_bounds__(256) void k_deg(const int* __restrict__ src, const int* __restrict__ dst,
                                             int* __restrict__ dout, int* __restrict__ din) {
    int e = blockIdx.x * 256 + threadIdx.x;
    if (e < NE) {
        atomicAdd(&dout[src[e]], 1);
        atomicAdd(&din[dst[e]], 1);
    }
}

__global__ __launch_bounds__(256) void k_norm(const int* __restrict__ dout, const int* __restrict__ din,
                                              float* __restrict__ ns, float* __restrict__ nd) {
    int i = blockIdx.x * 256 + threadIdx.x;
    if (i < NN) {
        ns[i] = 1.0f / sqrtf((float)max(dout[i], 1));
        nd[i] = 1.0f / sqrtf((float)max(din[i], 1));
    }
}

__global__ __launch_bounds__(256) void k_scanA(const int* __restrict__ din, int* __restrict__ incl,
                                               int* __restrict__ bsum) {
    __shared__ int lds[256];
    int i = blockIdx.x * 256 + threadIdx.x;
    int v = (i < NN) ? din[i] : 0;
    lds[threadIdx.x] = v;
    __syncthreads();
    for (int off = 1; off < 256; off <<= 1) {
        int t = (threadIdx.x >= off) ? lds[threadIdx.x - off] : 0;
        __syncthreads();
        lds[threadIdx.x] += t;
        __syncthreads();
    }
    if (i < NN) incl[i] = lds[threadIdx.x];
    if (threadIdx.x == 255) bsum[blockIdx.x] = lds[255];
}

__global__ __launch_bounds__(256) void k_scanB(int* __restrict__ bsum, int nb) {
    __shared__ int lds[256];
    int v = (threadIdx.x < nb) ? bsum[threadIdx.x] : 0;
    lds[threadIdx.x] = v;
    __syncthreads();
    for (int off = 1; off < 256; off <<= 1) {
        int t = (threadIdx.x >= off) ? lds[threadIdx.x - off] : 0;
        __syncthreads();
        lds[threadIdx.x] += t;
        __syncthreads();
    }
    if (threadIdx.x < nb) bsum[threadIdx.x] = lds[threadIdx.x] - v;  // exclusive
}

__global__ __launch_bounds__(256) void k_scanC(const int* __restrict__ incl, const int* __restrict__ din,
                                               const int* __restrict__ bsum, int* __restrict__ row_start,
                                               int* __restrict__ cursor) {
    int i = blockIdx.x * 256 + threadIdx.x;
    if (i < NN) {
        int rs = incl[i] - din[i] + bsum[i >> 8];
        row_start[i] = rs;
        cursor[i] = rs;
    }
}

__global__ __launch_bounds__(256) void k_fill(const int* __restrict__ src, const int* __restrict__ dst,
                                              int* __restrict__ cursor, int* __restrict__ col) {
    int e = blockIdx.x * 256 + threadIdx.x;
    if (e < NE) {
        int d = dst[e];
        int p = atomicAdd(&cursor[d], 1);
        col[p] = src[e];
    }
}

__global__ __launch_bounds__(256) void k_wprep(const float* __restrict__ W1, const float* __restrict__ W2,
                                               float* __restrict__ w1p, float* __restrict__ w2p) {
    int i = blockIdx.x * 256 + threadIdx.x;
    if (i < NL * HID * HID) {
        int l = i >> 12;
        int rc = i & 4095;
        int r = rc >> 6;
        int c = rc & 63;
        float beta = logf(0.5f / (float)(l + 1) + 1.0f);
        float d = (r == c) ? (1.0f - beta) : 0.0f;
        w1p[i] = beta * W1[i] + d;
        w2p[i] = beta * W2[i] + d;
    }
}

// ---------------- h0 GEMM: 512 thr (8 waves x 8 cols), double-buffered LDS staging ----------------
// 782 blocks -> ~3 blocks/CU -> 24 waves/CU (vs 12 before). Loads for tile t+1 issued before
// compute of tile t; written to the alternate buffer after the barrier -> HBM latency hidden.
__global__ __launch_bounds__(512) void k_gemm0(const float* __restrict__ feat, const float* __restrict__ Win,
                                               const float* __restrict__ bin, const float* __restrict__ ns,
                                               unsigned int* __restrict__ hs, unsigned int* __restrict__ f0b) {
    __shared__ float fS[2][64 * PADN];  // two 64-K slices, transposed [k][node]
    int tid = threadIdx.x;
    int lane = tid & 63;
    int wv = tid >> 6;  // 0..7
    int nb = blockIdx.x * 64;
    int cg = __builtin_amdgcn_readfirstlane(wv) * 8;  // 8 cols per wave, wave-uniform -> scalar weights
    float acc[8];
#pragma unroll
    for (int c = 0; c < 8; c++) acc[c] = 0.0f;

    float4 t[2];
    // prologue: stage tile 0
#pragma unroll
    for (int j = 0; j < 2; j++) {
        int i = tid + j * 512;
        int nl = i >> 4;
        int k4 = i & 15;
        int n = min(nb + nl, NN - 1);
        t[j] = *(const float4*)(feat + (size_t)n * INF + k4 * 4);
    }
#pragma unroll
    for (int j = 0; j < 2; j++) {
        int i = tid + j * 512;
        int nl = i >> 4;
        int k4 = i & 15;
        fS[0][(k4 * 4 + 0) * PADN + nl] = t[j].x;
        fS[0][(k4 * 4 + 1) * PADN + nl] = t[j].y;
        fS[0][(k4 * 4 + 2) * PADN + nl] = t[j].z;
        fS[0][(k4 * 4 + 3) * PADN + nl] = t[j].w;
    }
    __syncthreads();

    for (int kc = 0; kc < INF; kc += 64) {
        int cur = (kc >> 6) & 1;
        bool more = (kc + 64 < INF);
        // issue next tile's global loads BEFORE compute (latency hides under 64-k FMA phase)
        if (more) {
#pragma unroll
            for (int j = 0; j < 2; j++) {
                int i = tid + j * 512;
                int nl = i >> 4;
                int k4 = i & 15;
                int n = min(nb + nl, NN - 1);
                t[j] = *(const float4*)(feat + (size_t)n * INF + (kc + 64) + k4 * 4);
            }
        }
        const float* wb = Win + (size_t)kc * HID + cg;
        for (int k = 0; k < 64; ++k) {
            float fk = fS[cur][k * PADN + lane];
            const float* wr = wb + (size_t)k * HID;
#pragma unroll
            for (int c = 0; c < 8; c++) acc[c] += fk * wr[c];
        }
        if (more) {
            __syncthreads();  // all waves done reading fS[cur^1]'s previous contents
#pragma unroll
            for (int j = 0; j < 2; j++) {
                int i = tid + j * 512;
                int nl = i >> 4;
                int k4 = i & 15;
                fS[cur ^ 1][(k4 * 4 + 0) * PADN + nl] = t[j].x;
                fS[cur ^ 1][(k4 * 4 + 1) * PADN + nl] = t[j].y;
                fS[cur ^ 1][(k4 * 4 + 2) * PADN + nl] = t[j].z;
                fS[cur ^ 1][(k4 * 4 + 3) * PADN + nl] = t[j].w;
            }
            __syncthreads();  // next tile visible
        }
    }

    int node = nb + lane;
    if (node < NN) {
        float nsv = ns[node];
        const float* bp = bin + cg;
        float q[8];
#pragma unroll
        for (int c = 0; c < 8; c++) q[c] = fmaxf(acc[c] + bp[c], 0.0f);
        uint4 pk;
        pk.x = f2bf(q[0] * nsv) | (f2bf(q[1] * nsv) << 16);
        pk.y = f2bf(q[2] * nsv) | (f2bf(q[3] * nsv) << 16);
        pk.z = f2bf(q[4] * nsv) | (f2bf(q[5] * nsv) << 16);
        pk.w = f2bf(q[6] * nsv) | (f2bf(q[7] * nsv) << 16);
        *(uint4*)(hs + (size_t)node * 32 + cg / 2) = pk;
        uint4 pf;
        pf.x = f2bf(q[0] * 0.1f) | (f2bf(q[1] * 0.1f) << 16);
        pf.y = f2bf(q[2] * 0.1f) | (f2bf(q[3] * 0.1f) << 16);
        pf.z = f2bf(q[4] * 0.1f) | (f2bf(q[5] * 0.1f) << 16);
        pf.w = f2bf(q[6] * 0.1f) | (f2bf(q[7] * 0.1f) << 16);
        *(uint4*)(f0b + (size_t)node * 32 + cg / 2) = pf;
    }
}

// ---------------- fused layer: group-per-node agg (8 gathers in flight, col prefetch) + 8-wave matmul ----------------
// 512 threads = 8 waves. Block owns 64 dst-nodes. LDS = fT + f0T (33.3 KB -> 4 blocks/CU).
// pv[8] instead of pv[16] cuts peak VGPR pressure (goal: 8 waves/SIMD residency).
__global__ __launch_bounds__(512) void k_layer(const unsigned int* __restrict__ hs_in, const int* __restrict__ col,
                                               const int* __restrict__ row_start, const int* __restrict__ din,
                                               const float* __restrict__ nd, const unsigned int* __restrict__ f0b,
                                               const float* __restrict__ w1p, const float* __restrict__ w2p,
                                               const float* __restrict__ bias, const float* __restrict__ ns,
                                               float* __restrict__ h, unsigned int* __restrict__ hs_out, int write_h) {
    __shared__ float fT[HID * PADN];
    __shared__ float f0T[HID * PADN];
    int tid = threadIdx.x;
    int lane = tid & 63;
    int wv = tid >> 6;   // 0..7
    int nb = blockIdx.x * 64;
    int g = lane >> 4;   // group 0..3 (one node each)
    int ql = lane & 15;  // lane within group: owns dims [4ql, 4ql+4)

    // hoist both passes' metadata loads + first-chunk col indices to entry (off the critical chain)
    int nlP[2], baseP[2], degP[2], idxP[2];
    float ndP[2];
#pragma unroll
    for (int p = 0; p < 2; ++p) {
        int nl = wv * 8 + p * 4 + g;
        int n = min(nb + nl, NN - 1);
        nlP[p] = nl;
        baseP[p] = row_start[n];
        degP[p] = din[n];
        ndP[p] = nd[n];
    }
#pragma unroll
    for (int p = 0; p < 2; ++p) {
        idxP[p] = (ql < min(16, degP[p])) ? col[baseP[p] + ql] : 0;
    }

    // stage f0 (bf16) -> LDS transposed fp32
    for (int i = tid; i < 64 * 16; i += 512) {
        int nl = i >> 4;
        int q = i & 15;
        int n = min(nb + nl, NN - 1);
        uint2 v = *(const uint2*)(f0b + (size_t)n * 32 + q * 2);
        f0T[(q * 4 + 0) * PADN + nl] = bflo(v.x);
        f0T[(q * 4 + 1) * PADN + nl] = bfhi(v.x);
        f0T[(q * 4 + 2) * PADN + nl] = bflo(v.y);
        f0T[(q * 4 + 3) * PADN + nl] = bfhi(v.y);
    }

    // aggregation: each 16-lane group owns one node; 8 row-gathers in flight per batch
#pragma unroll
    for (int pass = 0; pass < 2; ++pass) {
        int base = baseP[pass];
        int deg = degP[pass];
        int idxv = idxP[pass];
        float ax = 0.0f, ay = 0.0f, az = 0.0f, aw = 0.0f;
        for (int done = 0; done < deg; done += 16) {
            int cnt = min(16, deg - done);  // uniform within the group
            // prefetch next chunk's indices while this chunk's gathers/adds run
            int nxt = done + 16;
            int idxn = 0;
            if (nxt < deg && ql < deg - nxt) idxn = col[base + nxt + ql];
            uint2 pv[8];
#pragma unroll
            for (int e = 0; e < 8; ++e) {
                int s = __shfl(idxv, (g << 4) | e, 64);
                uint2 v = {0u, 0u};
                if (e < cnt) v = *(const uint2*)(hs_in + (size_t)s * 32 + ql * 2);
                pv[e] = v;
            }
#pragma unroll
            for (int e = 0; e < 8; ++e) {
                ax += bflo(pv[e].x);
                ay += bfhi(pv[e].x);
                az += bflo(pv[e].y);
                aw += bfhi(pv[e].y);
            }
#pragma unroll
            for (int e = 0; e < 8; ++e) {
                int s = __shfl(idxv, (g << 4) | (8 + e), 64);
                uint2 v = {0u, 0u};
                if (8 + e < cnt) v = *(const uint2*)(hs_in + (size_t)s * 32 + ql * 2);
                pv[e] = v;
            }
#pragma unroll
            for (int e = 0; e < 8; ++e) {
                ax += bflo(pv[e].x);
                ay += bfhi(pv[e].x);
                az += bflo(pv[e].y);
                aw += bfhi(pv[e].y);
            }
            idxv = idxn;
        }
        float sc = 0.9f * ndP[pass];
        int nl = nlP[pass];
        // wave writes 4 nodes x 64 dims; banks (4ql+g) mod 32 -> exactly 2-way, free
        fT[(ql * 4 + 0) * PADN + nl] = ax * sc;
        fT[(ql * 4 + 1) * PADN + nl] = ay * sc;
        fT[(ql * 4 + 2) * PADN + nl] = az * sc;
        fT[(ql * 4 + 3) * PADN + nl] = aw * sc;
    }
    __syncthreads();

    // matmul: lane = node, wave = 8-col group; weights wave-uniform -> scalar loads
    int cg = __builtin_amdgcn_readfirstlane(wv) * 8;
    const float* w1b = w1p + cg;
    const float* w2b = w2p + cg;
    float acc[8];
#pragma unroll
    for (int c = 0; c < 8; c++) acc[c] = 0.0f;
    for (int k = 0; k < HID; ++k) {
        float fk = fT[k * PADN + lane];
        float f0k = f0T[k * PADN + lane];
        const float* w1r = w1b + (size_t)k * HID;
        const float* w2r = w2b + (size_t)k * HID;
#pragma unroll
        for (int c = 0; c < 8; c++) acc[c] += fk * w1r[c] + f0k * w2r[c];
    }
    int node = nb + lane;
    if (node < NN) {
        float nsv = ns[node];
        const float* bp = bias + cg;
        float q[8];
#pragma unroll
        for (int c = 0; c < 8; c++) q[c] = fmaxf(acc[c] + bp[c], 0.0f);
        uint2* hsp = (uint2*)(hs_out + (size_t)node * 32 + cg / 2);
#pragma unroll
        for (int c4 = 0; c4 < 2; c4++) {
            uint2 pk;
            pk.x = f2bf(q[c4 * 4 + 0] * nsv) | (f2bf(q[c4 * 4 + 1] * nsv) << 16);
            pk.y = f2bf(q[c4 * 4 + 2] * nsv) | (f2bf(q[c4 * 4 + 3] * nsv) << 16);
            hsp[c4] = pk;
        }
        if (write_h) {
            float4* hp = (float4*)(h + (size_t)node * HID + cg);
            float4 v0 = {q[0], q[1], q[2], q[3]};
            float4 v1 = {q[4], q[5], q[6], q[7]};
            hp[0] = v0;
            hp[1] = v1;
        }
    }
}

// ---------------- output: block = 128 nodes; wave pair splits the 40 cols; LDS lse reduce ----------------
__global__ __launch_bounds__(256) void k_out(const float* __restrict__ h, const float* __restrict__ Wout,
                                             const float* __restrict__ bout, float* __restrict__ out) {
    __shared__ float red_mx[4][64];
    __shared__ float red_s[4][64];
    int tid = threadIdx.x;
    int lane = tid & 63;
    int wv = tid >> 6;
    int half = wv & 1;
    int grp = wv >> 1;
    int node = blockIdx.x * 128 + grp * 64 + lane;
    int nodec = min(node, NN - 1);
    float acc[20];
#pragma unroll
    for (int c = 0; c < 20; c++) acc[c] = 0.0f;
    const float4* hr = (const float4*)(h + (size_t)nodec * HID);
    const float* wb = Wout + half * 20;
    for (int kk = 0; kk < HID / 4; ++kk) {
        float4 a = hr[kk];
        float av[4] = {a.x, a.y, a.z, a.w};
#pragma unroll
        for (int j = 0; j < 4; j++) {
            const float* wr = wb + (size_t)(kk * 4 + j) * OUTF;
#pragma unroll
            for (int c = 0; c < 20; c++) acc[c] += av[j] * wr[c];
        }
    }
    const float* bp = bout + half * 20;
#pragma unroll
    for (int c = 0; c < 20; c++) acc[c] += bp[c];
    float mx = acc[0];
#pragma unroll
    for (int c = 1; c < 20; c++) mx = fmaxf(mx, acc[c]);
    red_mx[wv][lane] = mx;
    __syncthreads();
    float gmx = fmaxf(mx, red_mx[wv ^ 1][lane]);
    float s = 0.0f;
#pragma unroll
    for (int c = 0; c < 20; c++) s += expf(acc[c] - gmx);
    red_s[wv][lane] = s;
    __syncthreads();
    float lse = logf(s + red_s[wv ^ 1][lane]) + gmx;
    if (node < NN) {
        float4* op = (float4*)(out + (size_t)node * OUTF + half * 20);
#pragma unroll
        for (int q = 0; q < 5; q++) {
            float4 v;
            v.x = acc[q * 4 + 0] - lse;
            v.y = acc[q * 4 + 1] - lse;
            v.z = acc[q * 4 + 2] - lse;
            v.w = acc[q * 4 + 3] - lse;
            op[q] = v;
        }
    }
}

extern "C" void kernel_launch(void* const* d_in, const int* in_sizes, int n_in,
                              void* d_out, int out_size, void* d_ws, size_t ws_size,
                              hipStream_t stream) {
    const float* feat = (const float*)d_in[0];
    const float* Win  = (const float*)d_in[1];
    const float* bin  = (const float*)d_in[2];
    const float* W1   = (const float*)d_in[3];
    const float* W2   = (const float*)d_in[4];
    const float* bvec = (const float*)d_in[5];
    const float* Wout = (const float*)d_in[6];
    const float* bout = (const float*)d_in[7];
    const int*   src  = (const int*)d_in[8];
    const int*   dst  = (const int*)d_in[9];
    float* out = (float*)d_out;

    char* ws = (char*)d_ws;
    size_t off = 0;
    auto take = [&](size_t bytes) {
        void* p = ws + off;
        off += (bytes + 255) & ~(size_t)255;
        return p;
    };
    int* deg_out   = (int*)take(NN * 4);
    int* deg_in    = (int*)take(NN * 4);
    int* incl      = (int*)take(NN * 4);
    int* bsum      = (int*)take(256 * 4);
    int* row_start = (int*)take(NN * 4);
    int* cursor    = (int*)take(NN * 4);
    int* col       = (int*)take(NE * 4);
    float* nsrc    = (float*)take(NN * 4);
    float* ndst    = (float*)take(NN * 4);
    float* w1p     = (float*)take((size_t)NL * HID * HID * 4);
    float* w2p     = (float*)take((size_t)NL * HID * HID * 4);
    unsigned int* f0b = (unsigned int*)take((size_t)NN * HID * 2);  // bf16
    float* hbuf    = (float*)take((size_t)NN * HID * 4);
    unsigned int* hsA = (unsigned int*)take((size_t)NN * HID * 2);  // bf16
    unsigned int* hsB = (unsigned int*)take((size_t)NN * HID * 2);  // bf16

    const int NB_N = (NN + 255) / 256;   // 196
    const int NB_E = (NE + 255) / 256;   // 3125
    const int NB_W = (NN + 63) / 64;     // 782
    const int NB_O = (NN + 127) / 128;   // 391

    hipMemsetAsync(deg_out, 0, NN * 4, stream);
    hipMemsetAsync(deg_in, 0, NN * 4, stream);

    k_deg<<<NB_E, 256, 0, stream>>>(src, dst, deg_out, deg_in);
    k_norm<<<NB_N, 256, 0, stream>>>(deg_out, deg_in, nsrc, ndst);
    k_scanA<<<NB_N, 256, 0, stream>>>(deg_in, incl, bsum);
    k_scanB<<<1, 256, 0, stream>>>(bsum, NB_N);
    k_scanC<<<NB_N, 256, 0, stream>>>(incl, deg_in, bsum, row_start, cursor);
    k_fill<<<NB_E, 256, 0, stream>>>(src, dst, cursor, col);
    k_wprep<<<(NL * HID * HID + 255) / 256, 256, 0, stream>>>(W1, W2, w1p, w2p);
    k_gemm0<<<NB_W, 512, 0, stream>>>(feat, Win, bin, nsrc, hsA, f0b);

    // ping-pong bf16 hs buffers (gathers read arbitrary rows; in-place would race)
    for (int l = 0; l < NL; ++l) {
        const unsigned int* hin = (l & 1) ? hsB : hsA;
        unsigned int* hout = (l & 1) ? hsA : hsB;
        k_layer<<<NB_W, 512, 0, stream>>>(hin, col, row_start, deg_in, ndst, f0b,
                                          w1p + l * HID * HID, w2p + l * HID * HID,
                                          bvec + l * HID, nsrc, hbuf, hout, (l == NL - 1) ? 1 : 0);
    }
    k_out<<<NB_O, 256, 0, stream>>>(hbuf, Wout, bout, out);
}

// Round 2
// 977.504 us; speedup vs baseline: 1.2906x; 1.2906x over previous
//
#include <hip/hip_runtime.h>
#include <math.h>

#define NN 50000
#define NE 800000
#define INF 512
#define HID 64
#define OUTF 40
#define NL 16
#define PADN 65

// bf16 helpers: RNE pack, cheap unpack
__device__ __forceinline__ unsigned int f2bf(float f) {
    unsigned int u = __float_as_uint(f);
    return (u + 0x7fffu + ((u >> 16) & 1u)) >> 16;
}
__device__ __forceinline__ float bflo(unsigned int w) { return __uint_as_float(w << 16); }
__device__ __forceinline__ float bfhi(unsigned int w) { return __uint_as_float(w & 0xffff0000u); }

// ---------------- setup kernels ----------------

__global__ __launch_bounds__(256) void k_deg(const int* __restrict__ src, const int* __restrict__ dst,
                                             int* __restrict__ dout, int* __restrict__ din) {
    int e = blockIdx.x * 256 + threadIdx.x;
    if (e < NE) {
        atomicAdd(&dout[src[e]], 1);
        atomicAdd(&din[dst[e]], 1);
    }
}

__global__ __launch_bounds__(256) void k_norm(const int* __restrict__ dout, const int* __restrict__ din,
                                              float* __restrict__ ns, float* __restrict__ nd) {
    int i = blockIdx.x * 256 + threadIdx.x;
    if (i < NN) {
        ns[i] = 1.0f / sqrtf((float)max(dout[i], 1));
        nd[i] = 1.0f / sqrtf((float)max(din[i], 1));
    }
}

__global__ __launch_bounds__(256) void k_scanA(const int* __restrict__ din, int* __restrict__ incl,
                                               int* __restrict__ bsum) {
    __shared__ int lds[256];
    int i = blockIdx.x * 256 + threadIdx.x;
    int v = (i < NN) ? din[i] : 0;
    lds[threadIdx.x] = v;
    __syncthreads();
    for (int off = 1; off < 256; off <<= 1) {
        int t = (threadIdx.x >= off) ? lds[threadIdx.x - off] : 0;
        __syncthreads();
        lds[threadIdx.x] += t;
        __syncthreads();
    }
    if (i < NN) incl[i] = lds[threadIdx.x];
    if (threadIdx.x == 255) bsum[blockIdx.x] = lds[255];
}

__global__ __launch_bounds__(256) void k_scanB(int* __restrict__ bsum, int nb) {
    __shared__ int lds[256];
    int v = (threadIdx.x < nb) ? bsum[threadIdx.x] : 0;
    lds[threadIdx.x] = v;
    __syncthreads();
    for (int off = 1; off < 256; off <<= 1) {
        int t = (threadIdx.x >= off) ? lds[threadIdx.x - off] : 0;
        __syncthreads();
        lds[threadIdx.x] += t;
        __syncthreads();
    }
    if (threadIdx.x < nb) bsum[threadIdx.x] = lds[threadIdx.x] - v;  // exclusive
}

__global__ __launch_bounds__(256) void k_scanC(const int* __restrict__ incl, const int* __restrict__ din,
                                               const int* __restrict__ bsum, int* __restrict__ row_start,
                                               int* __restrict__ cursor) {
    int i = blockIdx.x * 256 + threadIdx.x;
    if (i < NN) {
        int rs = incl[i] - din[i] + bsum[i >> 8];
        row_start[i] = rs;
        cursor[i] = rs;
    }
}

__global__ __launch_bounds__(256) void k_fill(const int* __restrict__ src, const int* __restrict__ dst,
                                              int* __restrict__ cursor, int* __restrict__ col) {
    int e = blockIdx.x * 256 + threadIdx.x;
    if (e < NE) {
        int d = dst[e];
        int p = atomicAdd(&cursor[d], 1);
        col[p] = src[e];
    }
}

__global__ __launch_bounds__(256) void k_wprep(const float* __restrict__ W1, const float* __restrict__ W2,
                                               float* __restrict__ w1p, float* __restrict__ w2p) {
    int i = blockIdx.x * 256 + threadIdx.x;
    if (i < NL * HID * HID) {
        int l = i >> 12;
        int rc = i & 4095;
        int r = rc >> 6;
        int c = rc & 63;
        float beta = logf(0.5f / (float)(l + 1) + 1.0f);
        float d = (r == c) ? (1.0f - beta) : 0.0f;
        w1p[i] = beta * W1[i] + d;
        w2p[i] = beta * W2[i] + d;
    }
}

// ---------------- h0 GEMM: round-0 structure (VGPR 24, no spill), K-split x2 for 2x grid ----------------
// Block bx: node tile w = bx>>1, K-half kh = bx&1 (256 of 512 K). 1564 blocks -> ~6 blocks/CU
// (was 3.05, grid-limited at 34% occupancy). Writes fp32 partials; k_gfin combines.
__global__ __launch_bounds__(256) void k_gemm0(const float* __restrict__ feat, const float* __restrict__ Win,
                                               float* __restrict__ p0, float* __restrict__ p1) {
    __shared__ float fS[64 * PADN];  // 64-K slice, transposed [k][node]
    int tid = threadIdx.x;
    int lane = tid & 63;
    int wv = tid >> 6;
    int bx = blockIdx.x;
    int w = bx >> 1;
    int kh = bx & 1;
    int nb = w * 64;
    int cg = __builtin_amdgcn_readfirstlane(wv) * 16;
    float acc[16];
#pragma unroll
    for (int c = 0; c < 16; c++) acc[c] = 0.0f;

    int k0 = kh * 256;
    for (int kc = k0; kc < k0 + 256; kc += 64) {
        if (kc != k0) __syncthreads();
        // batched staging: 4 independent float4 loads in flight, then LDS writes
        float4 t[4];
#pragma unroll
        for (int j = 0; j < 4; j++) {
            int i = tid + j * 256;
            int nl = i >> 4;
            int k4 = i & 15;
            int n = min(nb + nl, NN - 1);
            t[j] = *(const float4*)(feat + (size_t)n * INF + kc + k4 * 4);
        }
#pragma unroll
        for (int j = 0; j < 4; j++) {
            int i = tid + j * 256;
            int nl = i >> 4;
            int k4 = i & 15;
            fS[(k4 * 4 + 0) * PADN + nl] = t[j].x;
            fS[(k4 * 4 + 1) * PADN + nl] = t[j].y;
            fS[(k4 * 4 + 2) * PADN + nl] = t[j].z;
            fS[(k4 * 4 + 3) * PADN + nl] = t[j].w;
        }
        __syncthreads();
        const float* wb = Win + (size_t)kc * HID + cg;
        for (int k = 0; k < 64; ++k) {
            float fk = fS[k * PADN + lane];
            const float* wr = wb + (size_t)k * HID;
#pragma unroll
            for (int c = 0; c < 16; c++) acc[c] += fk * wr[c];
        }
    }
    int node = nb + lane;
    if (node < NN) {
        float* pp = (kh ? p1 : p0) + (size_t)node * HID + cg;
#pragma unroll
        for (int c4 = 0; c4 < 4; c4++) {
            float4 v = {acc[c4 * 4 + 0], acc[c4 * 4 + 1], acc[c4 * 4 + 2], acc[c4 * 4 + 3]};
            *(float4*)(pp + c4 * 4) = v;
        }
    }
}

// combine: p0+p1, +bias, relu, ns-scale, bf16 pack -> hs, f0b. ~38 MB L2-hot traffic.
__global__ __launch_bounds__(256) void k_gfin(const float* __restrict__ p0, const float* __restrict__ p1,
                                              const float* __restrict__ bin, const float* __restrict__ ns,
                                              unsigned int* __restrict__ hs, unsigned int* __restrict__ f0b) {
    int i = blockIdx.x * 256 + threadIdx.x;  // quad index: node*16 + q
    if (i >= NN * 16) return;
    int node = i >> 4;
    int q = i & 15;
    float4 a = ((const float4*)p0)[i];
    float4 b = ((const float4*)p1)[i];
    float4 bi = ((const float4*)bin)[q];
    float nsv = ns[node];
    float q0 = fmaxf(a.x + b.x + bi.x, 0.0f);
    float q1 = fmaxf(a.y + b.y + bi.y, 0.0f);
    float q2 = fmaxf(a.z + b.z + bi.z, 0.0f);
    float q3 = fmaxf(a.w + b.w + bi.w, 0.0f);
    uint2 pk;
    pk.x = f2bf(q0 * nsv) | (f2bf(q1 * nsv) << 16);
    pk.y = f2bf(q2 * nsv) | (f2bf(q3 * nsv) << 16);
    *(uint2*)(hs + (size_t)node * 32 + q * 2) = pk;
    uint2 pf;
    pf.x = f2bf(q0 * 0.1f) | (f2bf(q1 * 0.1f) << 16);
    pf.y = f2bf(q2 * 0.1f) | (f2bf(q3 * 0.1f) << 16);
    *(uint2*)(f0b + (size_t)node * 32 + q * 2) = pf;
}

// ---------------- fused layer: group-per-node agg (8 gathers in flight, col prefetch) + 8-wave matmul ----------------
// 512 threads = 8 waves. Block owns 64 dst-nodes. LDS = fT + f0T (33.3 KB -> 4 blocks/CU).
__global__ __launch_bounds__(512) void k_layer(const unsigned int* __restrict__ hs_in, const int* __restrict__ col,
                                               const int* __restrict__ row_start, const int* __restrict__ din,
                                               const float* __restrict__ nd, const unsigned int* __restrict__ f0b,
                                               const float* __restrict__ w1p, const float* __restrict__ w2p,
                                               const float* __restrict__ bias, const float* __restrict__ ns,
                                               float* __restrict__ h, unsigned int* __restrict__ hs_out, int write_h) {
    __shared__ float fT[HID * PADN];
    __shared__ float f0T[HID * PADN];
    int tid = threadIdx.x;
    int lane = tid & 63;
    int wv = tid >> 6;   // 0..7
    int nb = blockIdx.x * 64;
    int g = lane >> 4;   // group 0..3 (one node each)
    int ql = lane & 15;  // lane within group: owns dims [4ql, 4ql+4)

    // hoist both passes' metadata loads + first-chunk col indices to entry (off the critical chain)
    int nlP[2], baseP[2], degP[2], idxP[2];
    float ndP[2];
#pragma unroll
    for (int p = 0; p < 2; ++p) {
        int nl = wv * 8 + p * 4 + g;
        int n = min(nb + nl, NN - 1);
        nlP[p] = nl;
        baseP[p] = row_start[n];
        degP[p] = din[n];
        ndP[p] = nd[n];
    }
#pragma unroll
    for (int p = 0; p < 2; ++p) {
        idxP[p] = (ql < min(16, degP[p])) ? col[baseP[p] + ql] : 0;
    }

    // stage f0 (bf16) -> LDS transposed fp32
    for (int i = tid; i < 64 * 16; i += 512) {
        int nl = i >> 4;
        int q = i & 15;
        int n = min(nb + nl, NN - 1);
        uint2 v = *(const uint2*)(f0b + (size_t)n * 32 + q * 2);
        f0T[(q * 4 + 0) * PADN + nl] = bflo(v.x);
        f0T[(q * 4 + 1) * PADN + nl] = bfhi(v.x);
        f0T[(q * 4 + 2) * PADN + nl] = bflo(v.y);
        f0T[(q * 4 + 3) * PADN + nl] = bfhi(v.y);
    }

    // aggregation: each 16-lane group owns one node; 8 row-gathers in flight per batch
#pragma unroll
    for (int pass = 0; pass < 2; ++pass) {
        int base = baseP[pass];
        int deg = degP[pass];
        int idxv = idxP[pass];
        float ax = 0.0f, ay = 0.0f, az = 0.0f, aw = 0.0f;
        for (int done = 0; done < deg; done += 16) {
            int cnt = min(16, deg - done);  // uniform within the group
            // prefetch next chunk's indices while this chunk's gathers/adds run
            int nxt = done + 16;
            int idxn = 0;
            if (nxt < deg && ql < deg - nxt) idxn = col[base + nxt + ql];
            uint2 pv[8];
#pragma unroll
            for (int e = 0; e < 8; ++e) {
                int s = __shfl(idxv, (g << 4) | e, 64);
                uint2 v = {0u, 0u};
                if (e < cnt) v = *(const uint2*)(hs_in + (size_t)s * 32 + ql * 2);
                pv[e] = v;
            }
#pragma unroll
            for (int e = 0; e < 8; ++e) {
                ax += bflo(pv[e].x);
                ay += bfhi(pv[e].x);
                az += bflo(pv[e].y);
                aw += bfhi(pv[e].y);
            }
#pragma unroll
            for (int e = 0; e < 8; ++e) {
                int s = __shfl(idxv, (g << 4) | (8 + e), 64);
                uint2 v = {0u, 0u};
                if (8 + e < cnt) v = *(const uint2*)(hs_in + (size_t)s * 32 + ql * 2);
                pv[e] = v;
            }
#pragma unroll
            for (int e = 0; e < 8; ++e) {
                ax += bflo(pv[e].x);
                ay += bfhi(pv[e].x);
                az += bflo(pv[e].y);
                aw += bfhi(pv[e].y);
            }
            idxv = idxn;
        }
        float sc = 0.9f * ndP[pass];
        int nl = nlP[pass];
        // wave writes 4 nodes x 64 dims; banks (4ql+g) mod 32 -> exactly 2-way, free
        fT[(ql * 4 + 0) * PADN + nl] = ax * sc;
        fT[(ql * 4 + 1) * PADN + nl] = ay * sc;
        fT[(ql * 4 + 2) * PADN + nl] = az * sc;
        fT[(ql * 4 + 3) * PADN + nl] = aw * sc;
    }
    __syncthreads();

    // matmul: lane = node, wave = 8-col group; weights wave-uniform -> scalar loads
    int cg = __builtin_amdgcn_readfirstlane(wv) * 8;
    const float* w1b = w1p + cg;
    const float* w2b = w2p + cg;
    float acc[8];
#pragma unroll
    for (int c = 0; c < 8; c++) acc[c] = 0.0f;
    for (int k = 0; k < HID; ++k) {
        float fk = fT[k * PADN + lane];
        float f0k = f0T[k * PADN + lane];
        const float* w1r = w1b + (size_t)k * HID;
        const float* w2r = w2b + (size_t)k * HID;
#pragma unroll
        for (int c = 0; c < 8; c++) acc[c] += fk * w1r[c] + f0k * w2r[c];
    }
    int node = nb + lane;
    if (node < NN) {
        float nsv = ns[node];
        const float* bp = bias + cg;
        float q[8];
#pragma unroll
        for (int c = 0; c < 8; c++) q[c] = fmaxf(acc[c] + bp[c], 0.0f);
        uint2* hsp = (uint2*)(hs_out + (size_t)node * 32 + cg / 2);
#pragma unroll
        for (int c4 = 0; c4 < 2; c4++) {
            uint2 pk;
            pk.x = f2bf(q[c4 * 4 + 0] * nsv) | (f2bf(q[c4 * 4 + 1] * nsv) << 16);
            pk.y = f2bf(q[c4 * 4 + 2] * nsv) | (f2bf(q[c4 * 4 + 3] * nsv) << 16);
            hsp[c4] = pk;
        }
        if (write_h) {
            float4* hp = (float4*)(h + (size_t)node * HID + cg);
            float4 v0 = {q[0], q[1], q[2], q[3]};
            float4 v1 = {q[4], q[5], q[6], q[7]};
            hp[0] = v0;
            hp[1] = v1;
        }
    }
}

// ---------------- output: block = 128 nodes; wave pair splits the 40 cols; LDS lse reduce ----------------
__global__ __launch_bounds__(256) void k_out(const float* __restrict__ h, const float* __restrict__ Wout,
                                             const float* __restrict__ bout, float* __restrict__ out) {
    __shared__ float red_mx[4][64];
    __shared__ float red_s[4][64];
    int tid = threadIdx.x;
    int lane = tid & 63;
    int wv = tid >> 6;
    int half = wv & 1;
    int grp = wv >> 1;
    int node = blockIdx.x * 128 + grp * 64 + lane;
    int nodec = min(node, NN - 1);
    float acc[20];
#pragma unroll
    for (int c = 0; c < 20; c++) acc[c] = 0.0f;
    const float4* hr = (const float4*)(h + (size_t)nodec * HID);
    const float* wb = Wout + half * 20;
    for (int kk = 0; kk < HID / 4; ++kk) {
        float4 a = hr[kk];
        float av[4] = {a.x, a.y, a.z, a.w};
#pragma unroll
        for (int j = 0; j < 4; j++) {
            const float* wr = wb + (size_t)(kk * 4 + j) * OUTF;
#pragma unroll
            for (int c = 0; c < 20; c++) acc[c] += av[j] * wr[c];
        }
    }
    const float* bp = bout + half * 20;
#pragma unroll
    for (int c = 0; c < 20; c++) acc[c] += bp[c];
    float mx = acc[0];
#pragma unroll
    for (int c = 1; c < 20; c++) mx = fmaxf(mx, acc[c]);
    red_mx[wv][lane] = mx;
    __syncthreads();
    float gmx = fmaxf(mx, red_mx[wv ^ 1][lane]);
    float s = 0.0f;
#pragma unroll
    for (int c = 0; c < 20; c++) s += expf(acc[c] - gmx);
    red_s[wv][lane] = s;
    __syncthreads();
    float lse = logf(s + red_s[wv ^ 1][lane]) + gmx;
    if (node < NN) {
        float4* op = (float4*)(out + (size_t)node * OUTF + half * 20);
#pragma unroll
        for (int q = 0; q < 5; q++) {
            float4 v;
            v.x = acc[q * 4 + 0] - lse;
            v.y = acc[q * 4 + 1] - lse;
            v.z = acc[q * 4 + 2] - lse;
            v.w = acc[q * 4 + 3] - lse;
            op[q] = v;
        }
    }
}

extern "C" void kernel_launch(void* const* d_in, const int* in_sizes, int n_in,
                              void* d_out, int out_size, void* d_ws, size_t ws_size,
                              hipStream_t stream) {
    const float* feat = (const float*)d_in[0];
    const float* Win  = (const float*)d_in[1];
    const float* bin  = (const float*)d_in[2];
    const float* W1   = (const float*)d_in[3];
    const float* W2   = (const float*)d_in[4];
    const float* bvec = (const float*)d_in[5];
    const float* Wout = (const float*)d_in[6];
    const float* bout = (const float*)d_in[7];
    const int*   src  = (const int*)d_in[8];
    const int*   dst  = (const int*)d_in[9];
    float* out = (float*)d_out;

    char* ws = (char*)d_ws;
    size_t off = 0;
    auto take = [&](size_t bytes) {
        void* p = ws + off;
        off += (bytes + 255) & ~(size_t)255;
        return p;
    };
    int* deg_out   = (int*)take(NN * 4);
    int* deg_in    = (int*)take(NN * 4);
    int* incl      = (int*)take(NN * 4);
    int* bsum      = (int*)take(256 * 4);
    int* row_start = (int*)take(NN * 4);
    int* cursor    = (int*)take(NN * 4);
    int* col       = (int*)take(NE * 4);
    float* nsrc    = (float*)take(NN * 4);
    float* ndst    = (float*)take(NN * 4);
    float* w1p     = (float*)take((size_t)NL * HID * HID * 4);
    float* w2p     = (float*)take((size_t)NL * HID * HID * 4);
    unsigned int* f0b = (unsigned int*)take((size_t)NN * HID * 2);  // bf16
    float* hbuf    = (float*)take((size_t)NN * HID * 4);            // doubles as gemm0 partial p0
    float* part1   = (float*)take((size_t)NN * HID * 4);            // gemm0 partial p1
    unsigned int* hsA = (unsigned int*)take((size_t)NN * HID * 2);  // bf16
    unsigned int* hsB = (unsigned int*)take((size_t)NN * HID * 2);  // bf16

    const int NB_N = (NN + 255) / 256;   // 196
    const int NB_E = (NE + 255) / 256;   // 3125
    const int NB_W = (NN + 63) / 64;     // 782
    const int NB_O = (NN + 127) / 128;   // 391

    hipMemsetAsync(deg_out, 0, NN * 4, stream);
    hipMemsetAsync(deg_in, 0, NN * 4, stream);

    k_deg<<<NB_E, 256, 0, stream>>>(src, dst, deg_out, deg_in);
    k_norm<<<NB_N, 256, 0, stream>>>(deg_out, deg_in, nsrc, ndst);
    k_scanA<<<NB_N, 256, 0, stream>>>(deg_in, incl, bsum);
    k_scanB<<<1, 256, 0, stream>>>(bsum, NB_N);
    k_scanC<<<NB_N, 256, 0, stream>>>(incl, deg_in, bsum, row_start, cursor);
    k_fill<<<NB_E, 256, 0, stream>>>(src, dst, cursor, col);
    k_wprep<<<(NL * HID * HID + 255) / 256, 256, 0, stream>>>(W1, W2, w1p, w2p);
    k_gemm0<<<2 * NB_W, 256, 0, stream>>>(feat, Win, hbuf, part1);
    k_gfin<<<(NN * 16 + 255) / 256, 256, 0, stream>>>(hbuf, part1, bin, nsrc, hsA, f0b);

    // ping-pong bf16 hs buffers (gathers read arbitrary rows; in-place would race)
    for (int l = 0; l < NL; ++l) {
        const unsigned int* hin = (l & 1) ? hsB : hsA;
        unsigned int* hout = (l & 1) ? hsA : hsB;
        k_layer<<<NB_W, 512, 0, stream>>>(hin, col, row_start, deg_in, ndst, f0b,
                                          w1p + l * HID * HID, w2p + l * HID * HID,
                                          bvec + l * HID, nsrc, hbuf, hout, (l == NL - 1) ? 1 : 0);
    }
    k_out<<<NB_O, 256, 0, stream>>>(hbuf, Wout, bout, out);
}

// Round 3
// 947.064 us; speedup vs baseline: 1.3321x; 1.0321x over previous
//
#include <hip/hip_runtime.h>
#include <math.h>

#define NN 50000
#define NE 800000
#define INF 512
#define HID 64
#define OUTF 40
#define NL 16
#define PADN 65

using short8 = __attribute__((ext_vector_type(8))) short;
using f32x4v = __attribute__((ext_vector_type(4))) float;

// bf16 helpers: RNE pack, cheap unpack
__device__ __forceinline__ unsigned int f2bf(float f) {
    unsigned int u = __float_as_uint(f);
    return (u + 0x7fffu + ((u >> 16) & 1u)) >> 16;
}
__device__ __forceinline__ float bflo(unsigned int w) { return __uint_as_float(w << 16); }
__device__ __forceinline__ float bfhi(unsigned int w) { return __uint_as_float(w & 0xffff0000u); }

// ---------------- setup kernels ----------------

__global__ __launch_bounds__(256) void k_deg(const int* __restrict__ src, const int* __restrict__ dst,
                                             int* __restrict__ dout, int* __restrict__ din) {
    int e = blockIdx.x * 256 + threadIdx.x;
    if (e < NE) {
        atomicAdd(&dout[src[e]], 1);
        atomicAdd(&din[dst[e]], 1);
    }
}

__global__ __launch_bounds__(256) void k_norm(const int* __restrict__ dout, const int* __restrict__ din,
                                              float* __restrict__ ns, float* __restrict__ nd) {
    int i = blockIdx.x * 256 + threadIdx.x;
    if (i < NN) {
        ns[i] = 1.0f / sqrtf((float)max(dout[i], 1));
        nd[i] = 1.0f / sqrtf((float)max(din[i], 1));
    }
}

__global__ __launch_bounds__(256) void k_scanA(const int* __restrict__ din, int* __restrict__ incl,
                                               int* __restrict__ bsum) {
    __shared__ int lds[256];
    int i = blockIdx.x * 256 + threadIdx.x;
    int v = (i < NN) ? din[i] : 0;
    lds[threadIdx.x] = v;
    __syncthreads();
    for (int off = 1; off < 256; off <<= 1) {
        int t = (threadIdx.x >= off) ? lds[threadIdx.x - off] : 0;
        __syncthreads();
        lds[threadIdx.x] += t;
        __syncthreads();
    }
    if (i < NN) incl[i] = lds[threadIdx.x];
    if (threadIdx.x == 255) bsum[blockIdx.x] = lds[255];
}

__global__ __launch_bounds__(256) void k_scanB(int* __restrict__ bsum, int nb) {
    __shared__ int lds[256];
    int v = (threadIdx.x < nb) ? bsum[threadIdx.x] : 0;
    lds[threadIdx.x] = v;
    __syncthreads();
    for (int off = 1; off < 256; off <<= 1) {
        int t = (threadIdx.x >= off) ? lds[threadIdx.x - off] : 0;
        __syncthreads();
        lds[threadIdx.x] += t;
        __syncthreads();
    }
    if (threadIdx.x < nb) bsum[threadIdx.x] = lds[threadIdx.x] - v;  // exclusive
}

__global__ __launch_bounds__(256) void k_scanC(const int* __restrict__ incl, const int* __restrict__ din,
                                               const int* __restrict__ bsum, int* __restrict__ row_start,
                                               int* __restrict__ cursor) {
    int i = blockIdx.x * 256 + threadIdx.x;
    if (i < NN) {
        int rs = incl[i] - din[i] + bsum[i >> 8];
        row_start[i] = rs;
        cursor[i] = rs;
    }
}

__global__ __launch_bounds__(256) void k_fill(const int* __restrict__ src, const int* __restrict__ dst,
                                              int* __restrict__ cursor, int* __restrict__ col) {
    int e = blockIdx.x * 256 + threadIdx.x;
    if (e < NE) {
        int d = dst[e];
        int p = atomicAdd(&cursor[d], 1);
        col[p] = src[e];
    }
}

__global__ __launch_bounds__(256) void k_wprep(const float* __restrict__ W1, const float* __restrict__ W2,
                                               float* __restrict__ w1p, float* __restrict__ w2p) {
    int i = blockIdx.x * 256 + threadIdx.x;
    if (i < NL * HID * HID) {
        int l = i >> 12;
        int rc = i & 4095;
        int r = rc >> 6;
        int c = rc & 63;
        float beta = logf(0.5f / (float)(l + 1) + 1.0f);
        float d = (r == c) ? (1.0f - beta) : 0.0f;
        w1p[i] = beta * W1[i] + d;
        w2p[i] = beta * W2[i] + d;
    }
}

// Win (512x64 fp32, k-major) -> fragment-ordered bf16 for mfma_f32_16x16x32_bf16 B operand.
// Layout: [kstep s 0..15][coltile c 0..3][lane l 0..63][j 0..7]; col=c*16+(l&15), k=s*32+8*(l>>4)+j.
__global__ __launch_bounds__(256) void k_wfrag(const float* __restrict__ Win, unsigned short* __restrict__ wf) {
    int o = blockIdx.x * 256 + threadIdx.x;
    if (o < 16 * 4 * 64 * 8) {
        int jj = o & 7;
        int l = (o >> 3) & 63;
        int c = (o >> 9) & 3;
        int s = o >> 11;
        int colg = c * 16 + (l & 15);
        int k = s * 32 + ((l >> 4) << 3) + jj;
        wf[o] = (unsigned short)f2bf(Win[k * HID + colg]);
    }
}

// ---------------- h0 GEMM: bf16 MFMA (16x16x32), fragment-ordered LDS, K-split x2 ----------------
// Block bx: node tile w = bx>>1, K-half kh = bx&1. 4 waves; wave wv owns nodes [16wv,16wv+16),
// computes 4 col-tiles of 16. Feat converted fp32->bf16 (RNE) during staging. fp32 partials out.
__global__ __launch_bounds__(256) void k_gemm0(const float* __restrict__ feat, const unsigned short* __restrict__ wf,
                                               float* __restrict__ p0, float* __restrict__ p1) {
    __shared__ unsigned int fS[2048];  // 8 KB: [s(2)][w(4)][lane(64)][4 uints = 8 bf16]
    int tid = threadIdx.x;
    int lane = tid & 63;
    int wv = tid >> 6;
    int bx = blockIdx.x;
    int w = bx >> 1;
    int kh = bx & 1;
    int nb = w * 64;
    f32x4v acc[4];
#pragma unroll
    for (int c = 0; c < 4; c++) acc[c] = {0.0f, 0.0f, 0.0f, 0.0f};

    int k0 = kh * 256;
    for (int kc = k0; kc < k0 + 256; kc += 64) {
        if (kc != k0) __syncthreads();
        // stage 64 nodes x 64 k: 4 float4 loads in flight, convert to bf16, fragment-ordered writes
        float4 t[4];
#pragma unroll
        for (int j = 0; j < 4; j++) {
            int i = tid + j * 256;
            int nl = i >> 4;
            int k4 = i & 15;
            int n = min(nb + nl, NN - 1);
            t[j] = *(const float4*)(feat + (size_t)n * INF + kc + k4 * 4);
        }
#pragma unroll
        for (int j = 0; j < 4; j++) {
            int i = tid + j * 256;
            int nl = i >> 4;
            int kl = (i & 15) * 4;             // k within tile: 0..60 step 4
            int s = kl >> 5;                   // K-step half
            int kk = kl & 31;                  // k within step
            int lslot = (nl & 15) | ((kk >> 3) << 4);
            int dstu = (((s * 4 + (nl >> 4)) * 64 + lslot) << 2) + ((kk & 4) >> 1);
            fS[dstu] = f2bf(t[j].x) | (f2bf(t[j].y) << 16);
            fS[dstu + 1] = f2bf(t[j].z) | (f2bf(t[j].w) << 16);
        }
        __syncthreads();
#pragma unroll
        for (int s = 0; s < 2; ++s) {
            int sg = (kc + s * 32) >> 5;  // global K-step 0..15
            short8 af = *(const short8*)&fS[((s * 4 + wv) * 64 + lane) << 2];
            short8 bf[4];
#pragma unroll
            for (int c = 0; c < 4; ++c)
                bf[c] = *(const short8*)(wf + ((size_t)(sg * 4 + c) * 64 + lane) * 8);
#pragma unroll
            for (int c = 0; c < 4; ++c)
                acc[c] = __builtin_amdgcn_mfma_f32_16x16x32_bf16(af, bf[c], acc[c], 0, 0, 0);
        }
    }
    // C layout (verified): col = lane&15, row = 4*(lane>>4)+reg
    float* p = kh ? p1 : p0;
    int nodeb = nb + (wv << 4) + ((lane >> 4) << 2);
    int colb = lane & 15;
#pragma unroll
    for (int r = 0; r < 4; ++r) {
        int node = nodeb + r;
        if (node < NN) {
            float* pp = p + (size_t)node * HID + colb;
#pragma unroll
            for (int c = 0; c < 4; ++c) pp[c * 16] = acc[c][r];
        }
    }
}

// combine: p0+p1, +bias, relu, ns-scale, bf16 pack -> hs, f0b. ~38 MB L2-hot traffic.
__global__ __launch_bounds__(256) void k_gfin(const float* __restrict__ p0, const float* __restrict__ p1,
                                              const float* __restrict__ bin, const float* __restrict__ ns,
                                              unsigned int* __restrict__ hs, unsigned int* __restrict__ f0b) {
    int i = blockIdx.x * 256 + threadIdx.x;  // quad index: node*16 + q
    if (i >= NN * 16) return;
    int node = i >> 4;
    int q = i & 15;
    float4 a = ((const float4*)p0)[i];
    float4 b = ((const float4*)p1)[i];
    float4 bi = ((const float4*)bin)[q];
    float nsv = ns[node];
    float q0 = fmaxf(a.x + b.x + bi.x, 0.0f);
    float q1 = fmaxf(a.y + b.y + bi.y, 0.0f);
    float q2 = fmaxf(a.z + b.z + bi.z, 0.0f);
    float q3 = fmaxf(a.w + b.w + bi.w, 0.0f);
    uint2 pk;
    pk.x = f2bf(q0 * nsv) | (f2bf(q1 * nsv) << 16);
    pk.y = f2bf(q2 * nsv) | (f2bf(q3 * nsv) << 16);
    *(uint2*)(hs + (size_t)node * 32 + q * 2) = pk;
    uint2 pf;
    pf.x = f2bf(q0 * 0.1f) | (f2bf(q1 * 0.1f) << 16);
    pf.y = f2bf(q2 * 0.1f) | (f2bf(q3 * 0.1f) << 16);
    *(uint2*)(f0b + (size_t)node * 32 + q * 2) = pf;
}

// ---------------- fused layer: group-per-node agg (8 gathers in flight, col prefetch) + 8-wave matmul ----------------
// 512 threads = 8 waves. Block owns 64 dst-nodes. LDS = fT + f0T (33.3 KB -> 4 blocks/CU).
__global__ __launch_bounds__(512) void k_layer(const unsigned int* __restrict__ hs_in, const int* __restrict__ col,
                                               const int* __restrict__ row_start, const int* __restrict__ din,
                                               const float* __restrict__ nd, const unsigned int* __restrict__ f0b,
                                               const float* __restrict__ w1p, const float* __restrict__ w2p,
                                               const float* __restrict__ bias, const float* __restrict__ ns,
                                               float* __restrict__ h, unsigned int* __restrict__ hs_out, int write_h) {
    __shared__ float fT[HID * PADN];
    __shared__ float f0T[HID * PADN];
    int tid = threadIdx.x;
    int lane = tid & 63;
    int wv = tid >> 6;   // 0..7
    int nb = blockIdx.x * 64;
    int g = lane >> 4;   // group 0..3 (one node each)
    int ql = lane & 15;  // lane within group: owns dims [4ql, 4ql+4)

    // hoist both passes' metadata loads + first-chunk col indices to entry (off the critical chain)
    int nlP[2], baseP[2], degP[2], idxP[2];
    float ndP[2];
#pragma unroll
    for (int p = 0; p < 2; ++p) {
        int nl = wv * 8 + p * 4 + g;
        int n = min(nb + nl, NN - 1);
        nlP[p] = nl;
        baseP[p] = row_start[n];
        degP[p] = din[n];
        ndP[p] = nd[n];
    }
#pragma unroll
    for (int p = 0; p < 2; ++p) {
        idxP[p] = (ql < min(16, degP[p])) ? col[baseP[p] + ql] : 0;
    }

    // stage f0 (bf16) -> LDS transposed fp32
    for (int i = tid; i < 64 * 16; i += 512) {
        int nl = i >> 4;
        int q = i & 15;
        int n = min(nb + nl, NN - 1);
        uint2 v = *(const uint2*)(f0b + (size_t)n * 32 + q * 2);
        f0T[(q * 4 + 0) * PADN + nl] = bflo(v.x);
        f0T[(q * 4 + 1) * PADN + nl] = bfhi(v.x);
        f0T[(q * 4 + 2) * PADN + nl] = bflo(v.y);
        f0T[(q * 4 + 3) * PADN + nl] = bfhi(v.y);
    }

    // aggregation: each 16-lane group owns one node; 8 row-gathers in flight per batch
#pragma unroll
    for (int pass = 0; pass < 2; ++pass) {
        int base = baseP[pass];
        int deg = degP[pass];
        int idxv = idxP[pass];
        float ax = 0.0f, ay = 0.0f, az = 0.0f, aw = 0.0f;
        for (int done = 0; done < deg; done += 16) {
            int cnt = min(16, deg - done);  // uniform within the group
            // prefetch next chunk's indices while this chunk's gathers/adds run
            int nxt = done + 16;
            int idxn = 0;
            if (nxt < deg && ql < deg - nxt) idxn = col[base + nxt + ql];
            uint2 pv[8];
#pragma unroll
            for (int e = 0; e < 8; ++e) {
                int s = __shfl(idxv, (g << 4) | e, 64);
                uint2 v = {0u, 0u};
                if (e < cnt) v = *(const uint2*)(hs_in + (size_t)s * 32 + ql * 2);
                pv[e] = v;
            }
#pragma unroll
            for (int e = 0; e < 8; ++e) {
                ax += bflo(pv[e].x);
                ay += bfhi(pv[e].x);
                az += bflo(pv[e].y);
                aw += bfhi(pv[e].y);
            }
#pragma unroll
            for (int e = 0; e < 8; ++e) {
                int s = __shfl(idxv, (g << 4) | (8 + e), 64);
                uint2 v = {0u, 0u};
                if (8 + e < cnt) v = *(const uint2*)(hs_in + (size_t)s * 32 + ql * 2);
                pv[e] = v;
            }
#pragma unroll
            for (int e = 0; e < 8; ++e) {
                ax += bflo(pv[e].x);
                ay += bfhi(pv[e].x);
                az += bflo(pv[e].y);
                aw += bfhi(pv[e].y);
            }
            idxv = idxn;
        }
        float sc = 0.9f * ndP[pass];
        int nl = nlP[pass];
        // wave writes 4 nodes x 64 dims; banks (4ql+g) mod 32 -> exactly 2-way, free
        fT[(ql * 4 + 0) * PADN + nl] = ax * sc;
        fT[(ql * 4 + 1) * PADN + nl] = ay * sc;
        fT[(ql * 4 + 2) * PADN + nl] = az * sc;
        fT[(ql * 4 + 3) * PADN + nl] = aw * sc;
    }
    __syncthreads();

    // matmul: lane = node, wave = 8-col group; weights wave-uniform -> scalar loads
    int cg = __builtin_amdgcn_readfirstlane(wv) * 8;
    const float* w1b = w1p + cg;
    const float* w2b = w2p + cg;
    float acc[8];
#pragma unroll
    for (int c = 0; c < 8; c++) acc[c] = 0.0f;
    for (int k = 0; k < HID; ++k) {
        float fk = fT[k * PADN + lane];
        float f0k = f0T[k * PADN + lane];
        const float* w1r = w1b + (size_t)k * HID;
        const float* w2r = w2b + (size_t)k * HID;
#pragma unroll
        for (int c = 0; c < 8; c++) acc[c] += fk * w1r[c] + f0k * w2r[c];
    }
    int node = nb + lane;
    if (node < NN) {
        float nsv = ns[node];
        const float* bp = bias + cg;
        float q[8];
#pragma unroll
        for (int c = 0; c < 8; c++) q[c] = fmaxf(acc[c] + bp[c], 0.0f);
        uint2* hsp = (uint2*)(hs_out + (size_t)node * 32 + cg / 2);
#pragma unroll
        for (int c4 = 0; c4 < 2; c4++) {
            uint2 pk;
            pk.x = f2bf(q[c4 * 4 + 0] * nsv) | (f2bf(q[c4 * 4 + 1] * nsv) << 16);
            pk.y = f2bf(q[c4 * 4 + 2] * nsv) | (f2bf(q[c4 * 4 + 3] * nsv) << 16);
            hsp[c4] = pk;
        }
        if (write_h) {
            float4* hp = (float4*)(h + (size_t)node * HID + cg);
            float4 v0 = {q[0], q[1], q[2], q[3]};
            float4 v1 = {q[4], q[5], q[6], q[7]};
            hp[0] = v0;
            hp[1] = v1;
        }
    }
}

// ---------------- output: block = 128 nodes; wave pair splits the 40 cols; LDS lse reduce ----------------
__global__ __launch_bounds__(256) void k_out(const float* __restrict__ h, const float* __restrict__ Wout,
                                             const float* __restrict__ bout, float* __restrict__ out) {
    __shared__ float red_mx[4][64];
    __shared__ float red_s[4][64];
    int tid = threadIdx.x;
    int lane = tid & 63;
    int wv = tid >> 6;
    int half = wv & 1;
    int grp = wv >> 1;
    int node = blockIdx.x * 128 + grp * 64 + lane;
    int nodec = min(node, NN - 1);
    float acc[20];
#pragma unroll
    for (int c = 0; c < 20; c++) acc[c] = 0.0f;
    const float4* hr = (const float4*)(h + (size_t)nodec * HID);
    const float* wb = Wout + half * 20;
    for (int kk = 0; kk < HID / 4; ++kk) {
        float4 a = hr[kk];
        float av[4] = {a.x, a.y, a.z, a.w};
#pragma unroll
        for (int j = 0; j < 4; j++) {
            const float* wr = wb + (size_t)(kk * 4 + j) * OUTF;
#pragma unroll
            for (int c = 0; c < 20; c++) acc[c] += av[j] * wr[c];
        }
    }
    const float* bp = bout + half * 20;
#pragma unroll
    for (int c = 0; c < 20; c++) acc[c] += bp[c];
    float mx = acc[0];
#pragma unroll
    for (int c = 1; c < 20; c++) mx = fmaxf(mx, acc[c]);
    red_mx[wv][lane] = mx;
    __syncthreads();
    float gmx = fmaxf(mx, red_mx[wv ^ 1][lane]);
    float s = 0.0f;
#pragma unroll
    for (int c = 0; c < 20; c++) s += expf(acc[c] - gmx);
    red_s[wv][lane] = s;
    __syncthreads();
    float lse = logf(s + red_s[wv ^ 1][lane]) + gmx;
    if (node < NN) {
        float4* op = (float4*)(out + (size_t)node * OUTF + half * 20);
#pragma unroll
        for (int q = 0; q < 5; q++) {
            float4 v;
            v.x = acc[q * 4 + 0] - lse;
            v.y = acc[q * 4 + 1] - lse;
            v.z = acc[q * 4 + 2] - lse;
            v.w = acc[q * 4 + 3] - lse;
            op[q] = v;
        }
    }
}

extern "C" void kernel_launch(void* const* d_in, const int* in_sizes, int n_in,
                              void* d_out, int out_size, void* d_ws, size_t ws_size,
                              hipStream_t stream) {
    const float* feat = (const float*)d_in[0];
    const float* Win  = (const float*)d_in[1];
    const float* bin  = (const float*)d_in[2];
    const float* W1   = (const float*)d_in[3];
    const float* W2   = (const float*)d_in[4];
    const float* bvec = (const float*)d_in[5];
    const float* Wout = (const float*)d_in[6];
    const float* bout = (const float*)d_in[7];
    const int*   src  = (const int*)d_in[8];
    const int*   dst  = (const int*)d_in[9];
    float* out = (float*)d_out;

    char* ws = (char*)d_ws;
    size_t off = 0;
    auto take = [&](size_t bytes) {
        void* p = ws + off;
        off += (bytes + 255) & ~(size_t)255;
        return p;
    };
    int* deg_out   = (int*)take(NN * 4);
    int* deg_in    = (int*)take(NN * 4);
    int* incl      = (int*)take(NN * 4);
    int* bsum      = (int*)take(256 * 4);
    int* row_start = (int*)take(NN * 4);
    int* cursor    = (int*)take(NN * 4);
    int* col       = (int*)take(NE * 4);
    float* nsrc    = (float*)take(NN * 4);
    float* ndst    = (float*)take(NN * 4);
    float* w1p     = (float*)take((size_t)NL * HID * HID * 4);
    float* w2p     = (float*)take((size_t)NL * HID * HID * 4);
    unsigned short* wfrag = (unsigned short*)take((size_t)INF * HID * 2);  // frag-ordered bf16 Win
    unsigned int* f0b = (unsigned int*)take((size_t)NN * HID * 2);  // bf16
    float* hbuf    = (float*)take((size_t)NN * HID * 4);            // doubles as gemm0 partial p0
    float* part1   = (float*)take((size_t)NN * HID * 4);            // gemm0 partial p1
    unsigned int* hsA = (unsigned int*)take((size_t)NN * HID * 2);  // bf16
    unsigned int* hsB = (unsigned int*)take((size_t)NN * HID * 2);  // bf16

    const int NB_N = (NN + 255) / 256;   // 196
    const int NB_E = (NE + 255) / 256;   // 3125
    const int NB_W = (NN + 63) / 64;     // 782
    const int NB_O = (NN + 127) / 128;   // 391

    hipMemsetAsync(deg_out, 0, NN * 4, stream);
    hipMemsetAsync(deg_in, 0, NN * 4, stream);

    k_deg<<<NB_E, 256, 0, stream>>>(src, dst, deg_out, deg_in);
    k_norm<<<NB_N, 256, 0, stream>>>(deg_out, deg_in, nsrc, ndst);
    k_scanA<<<NB_N, 256, 0, stream>>>(deg_in, incl, bsum);
    k_scanB<<<1, 256, 0, stream>>>(bsum, NB_N);
    k_scanC<<<NB_N, 256, 0, stream>>>(incl, deg_in, bsum, row_start, cursor);
    k_fill<<<NB_E, 256, 0, stream>>>(src, dst, cursor, col);
    k_wprep<<<(NL * HID * HID + 255) / 256, 256, 0, stream>>>(W1, W2, w1p, w2p);
    k_wfrag<<<(INF * HID + 255) / 256, 256, 0, stream>>>(Win, wfrag);
    k_gemm0<<<2 * NB_W, 256, 0, stream>>>(feat, wfrag, hbuf, part1);
    k_gfin<<<(NN * 16 + 255) / 256, 256, 0, stream>>>(hbuf, part1, bin, nsrc, hsA, f0b);

    // ping-pong bf16 hs buffers (gathers read arbitrary rows; in-place would race)
    for (int l = 0; l < NL; ++l) {
        const unsigned int* hin = (l & 1) ? hsB : hsA;
        unsigned int* hout = (l & 1) ? hsA : hsB;
        k_layer<<<NB_W, 512, 0, stream>>>(hin, col, row_start, deg_in, ndst, f0b,
                                          w1p + l * HID * HID, w2p + l * HID * HID,
                                          bvec + l * HID, nsrc, hbuf, hout, (l == NL - 1) ? 1 : 0);
    }
    k_out<<<NB_O, 256, 0, stream>>>(hbuf, Wout, bout, out);
}

// Round 4
// 876.016 us; speedup vs baseline: 1.4402x; 1.0811x over previous
//
#include <hip/hip_runtime.h>
#include <math.h>

#define NN 50000
#define NE 800000
#define INF 512
#define HID 64
#define OUTF 40
#define NL 16
#define PADN 65

// bucketed CSR build parameters
#define NBLK 256      // edge-blocks; NE = NBLK * EPB exactly
#define EPB 3125
#define NBUK 196      // node buckets of 256 (node >> 8); 196*256 = 50176 >= NN
#define SLEN (NBUK * NBLK)  // 50176 count/offset entries

using short8 = __attribute__((ext_vector_type(8))) short;
using f32x4v = __attribute__((ext_vector_type(4))) float;

// bf16 helpers: RNE pack, cheap unpack
__device__ __forceinline__ unsigned int f2bf(float f) {
    unsigned int u = __float_as_uint(f);
    return (u + 0x7fffu + ((u >> 16) & 1u)) >> 16;
}
__device__ __forceinline__ float bflo(unsigned int w) { return __uint_as_float(w << 16); }
__device__ __forceinline__ float bfhi(unsigned int w) { return __uint_as_float(w & 0xffff0000u); }

// ---------------- bucketed CSR build (no global atomics) ----------------

// per-(bucket, edge-block) counts for dst and src
__global__ __launch_bounds__(256) void k_cnt(const int* __restrict__ src, const int* __restrict__ dst,
                                             int* __restrict__ cntD, int* __restrict__ cntS) {
    __shared__ int hD[NBUK];
    __shared__ int hS[NBUK];
    int t = threadIdx.x;
    int blk = blockIdx.x;
    if (t < NBUK) { hD[t] = 0; hS[t] = 0; }
    __syncthreads();
    int s0 = blk * EPB;
    for (int i = t; i < EPB; i += 256) {
        int e = s0 + i;
        atomicAdd(&hD[dst[e] >> 8], 1);
        atomicAdd(&hS[src[e] >> 8], 1);
    }
    __syncthreads();
    if (t < NBUK) {
        cntD[t * NBLK + blk] = hD[t];
        cntS[t * NBLK + blk] = hS[t];
    }
}

// generic scan trio (Hillis-Steele per block + block-sum fixup), exclusive result in off[]
__global__ __launch_bounds__(256) void gscanA(const int* __restrict__ in, int* __restrict__ incl,
                                              int* __restrict__ bsum, int len) {
    __shared__ int lds[256];
    int i = blockIdx.x * 256 + threadIdx.x;
    int v = (i < len) ? in[i] : 0;
    lds[threadIdx.x] = v;
    __syncthreads();
    for (int off = 1; off < 256; off <<= 1) {
        int t = (threadIdx.x >= off) ? lds[threadIdx.x - off] : 0;
        __syncthreads();
        lds[threadIdx.x] += t;
        __syncthreads();
    }
    if (i < len) incl[i] = lds[threadIdx.x];
    if (threadIdx.x == 255) bsum[blockIdx.x] = lds[255];
}

__global__ __launch_bounds__(256) void gscanB(int* __restrict__ bsum, int nb) {
    __shared__ int lds[256];
    int v = (threadIdx.x < nb) ? bsum[threadIdx.x] : 0;
    lds[threadIdx.x] = v;
    __syncthreads();
    for (int off = 1; off < 256; off <<= 1) {
        int t = (threadIdx.x >= off) ? lds[threadIdx.x - off] : 0;
        __syncthreads();
        lds[threadIdx.x] += t;
        __syncthreads();
    }
    if (threadIdx.x < nb) bsum[threadIdx.x] = lds[threadIdx.x] - v;  // exclusive
}

__global__ __launch_bounds__(256) void gscanC(const int* __restrict__ incl, const int* __restrict__ in,
                                              const int* __restrict__ bsum, int* __restrict__ off, int len) {
    int i = blockIdx.x * 256 + threadIdx.x;
    if (i < len) off[i] = incl[i] - in[i] + bsum[i >> 8];
}

// scatter edges into bucket order: edst[(dst-bucket order)] = (dst,src); esrc[(src-bucket order)] = src.
// plain stores (L2 write-combined: per-(bucket,block) runs are contiguous), LDS cursors only.
__global__ __launch_bounds__(256) void k_scat(const int* __restrict__ src, const int* __restrict__ dst,
                                              const int* __restrict__ offD, const int* __restrict__ offS,
                                              uint2* __restrict__ edst, int* __restrict__ esrc) {
    __shared__ int cD[NBUK];
    __shared__ int cS[NBUK];
    int t = threadIdx.x;
    int blk = blockIdx.x;
    if (t < NBUK) { cD[t] = 0; cS[t] = 0; }
    __syncthreads();
    int s0 = blk * EPB;
    for (int i = t; i < EPB; i += 256) {
        int e = s0 + i;
        int d = dst[e];
        int s = src[e];
        int bD = d >> 8;
        int r = atomicAdd(&cD[bD], 1);
        uint2 v;
        v.x = (unsigned)d;
        v.y = (unsigned)s;
        edst[offD[bD * NBLK + blk] + r] = v;
        int bS = s >> 8;
        int r2 = atomicAdd(&cS[bS], 1);
        esrc[offS[bS * NBLK + blk] + r2] = s;
    }
}

// one block per dst-bucket: din, nd, row_start, col — all LDS-local
__global__ __launch_bounds__(256) void k_bcsr(const uint2* __restrict__ edst, const int* __restrict__ offD,
                                              int* __restrict__ din, float* __restrict__ nd,
                                              int* __restrict__ row_start, int* __restrict__ col) {
    __shared__ int cnt[256];
    __shared__ int ex[256];
    __shared__ int cur[256];
    int b = blockIdx.x;
    int t = threadIdx.x;
    int base = offD[b * NBLK];
    int end = (b < NBUK - 1) ? offD[(b + 1) * NBLK] : NE;
    cnt[t] = 0;
    __syncthreads();
    for (int p = base + t; p < end; p += 256) {
        uint2 ed = edst[p];
        atomicAdd(&cnt[ed.x & 255], 1);
    }
    __syncthreads();
    int v = cnt[t];
    ex[t] = v;
    __syncthreads();
    for (int off = 1; off < 256; off <<= 1) {
        int tv = (t >= off) ? ex[t - off] : 0;
        __syncthreads();
        ex[t] += tv;
        __syncthreads();
    }
    int excl = ex[t] - v;
    cur[t] = excl;
    int node = b * 256 + t;
    if (node < NN) {
        din[node] = v;
        nd[node] = 1.0f / sqrtf((float)max(v, 1));
        row_start[node] = base + excl;
    }
    __syncthreads();
    for (int p = base + t; p < end; p += 256) {
        uint2 ed = edst[p];
        int r = atomicAdd(&cur[ed.x & 255], 1);
        col[base + r] = (int)ed.y;
    }
}

// one block per src-bucket: ns only
__global__ __launch_bounds__(256) void k_bns(const int* __restrict__ esrc, const int* __restrict__ offS,
                                             float* __restrict__ ns) {
    __shared__ int cnt[256];
    int b = blockIdx.x;
    int t = threadIdx.x;
    int base = offS[b * NBLK];
    int end = (b < NBUK - 1) ? offS[(b + 1) * NBLK] : NE;
    cnt[t] = 0;
    __syncthreads();
    for (int p = base + t; p < end; p += 256) {
        atomicAdd(&cnt[esrc[p] & 255], 1);
    }
    __syncthreads();
    int node = b * 256 + t;
    if (node < NN) ns[node] = 1.0f / sqrtf((float)max(cnt[t], 1));
}

// ---------------- weight prep ----------------

__global__ __launch_bounds__(256) void k_wprep(const float* __restrict__ W1, const float* __restrict__ W2,
                                               float* __restrict__ w1p, float* __restrict__ w2p) {
    int i = blockIdx.x * 256 + threadIdx.x;
    if (i < NL * HID * HID) {
        int l = i >> 12;
        int rc = i & 4095;
        int r = rc >> 6;
        int c = rc & 63;
        float beta = logf(0.5f / (float)(l + 1) + 1.0f);
        float d = (r == c) ? (1.0f - beta) : 0.0f;
        w1p[i] = beta * W1[i] + d;
        w2p[i] = beta * W2[i] + d;
    }
}

// Win (512x64 fp32, k-major) -> fragment-ordered bf16 for mfma_f32_16x16x32_bf16 B operand.
// Layout: [kstep s 0..15][coltile c 0..3][lane l 0..63][j 0..7]; col=c*16+(l&15), k=s*32+8*(l>>4)+j.
__global__ __launch_bounds__(256) void k_wfrag(const float* __restrict__ Win, unsigned short* __restrict__ wf) {
    int o = blockIdx.x * 256 + threadIdx.x;
    if (o < 16 * 4 * 64 * 8) {
        int jj = o & 7;
        int l = (o >> 3) & 63;
        int c = (o >> 9) & 3;
        int s = o >> 11;
        int colg = c * 16 + (l & 15);
        int k = s * 32 + ((l >> 4) << 3) + jj;
        wf[o] = (unsigned short)f2bf(Win[k * HID + colg]);
    }
}

// ---------------- h0 GEMM: bf16 MFMA (16x16x32), fragment-ordered LDS, K-split x2 ----------------
__global__ __launch_bounds__(256) void k_gemm0(const float* __restrict__ feat, const unsigned short* __restrict__ wf,
                                               float* __restrict__ p0, float* __restrict__ p1) {
    __shared__ unsigned int fS[2048];  // 8 KB: [s(2)][w(4)][lane(64)][4 uints = 8 bf16]
    int tid = threadIdx.x;
    int lane = tid & 63;
    int wv = tid >> 6;
    int bx = blockIdx.x;
    int w = bx >> 1;
    int kh = bx & 1;
    int nb = w * 64;
    f32x4v acc[4];
#pragma unroll
    for (int c = 0; c < 4; c++) acc[c] = {0.0f, 0.0f, 0.0f, 0.0f};

    int k0 = kh * 256;
    for (int kc = k0; kc < k0 + 256; kc += 64) {
        if (kc != k0) __syncthreads();
        float4 t[4];
#pragma unroll
        for (int j = 0; j < 4; j++) {
            int i = tid + j * 256;
            int nl = i >> 4;
            int k4 = i & 15;
            int n = min(nb + nl, NN - 1);
            t[j] = *(const float4*)(feat + (size_t)n * INF + kc + k4 * 4);
        }
#pragma unroll
        for (int j = 0; j < 4; j++) {
            int i = tid + j * 256;
            int nl = i >> 4;
            int kl = (i & 15) * 4;
            int s = kl >> 5;
            int kk = kl & 31;
            int lslot = (nl & 15) | ((kk >> 3) << 4);
            int dstu = (((s * 4 + (nl >> 4)) * 64 + lslot) << 2) + ((kk & 4) >> 1);
            fS[dstu] = f2bf(t[j].x) | (f2bf(t[j].y) << 16);
            fS[dstu + 1] = f2bf(t[j].z) | (f2bf(t[j].w) << 16);
        }
        __syncthreads();
#pragma unroll
        for (int s = 0; s < 2; ++s) {
            int sg = (kc + s * 32) >> 5;
            short8 af = *(const short8*)&fS[((s * 4 + wv) * 64 + lane) << 2];
            short8 bf[4];
#pragma unroll
            for (int c = 0; c < 4; ++c)
                bf[c] = *(const short8*)(wf + ((size_t)(sg * 4 + c) * 64 + lane) * 8);
#pragma unroll
            for (int c = 0; c < 4; ++c)
                acc[c] = __builtin_amdgcn_mfma_f32_16x16x32_bf16(af, bf[c], acc[c], 0, 0, 0);
        }
    }
    float* p = kh ? p1 : p0;
    int nodeb = nb + (wv << 4) + ((lane >> 4) << 2);
    int colb = lane & 15;
#pragma unroll
    for (int r = 0; r < 4; ++r) {
        int node = nodeb + r;
        if (node < NN) {
            float* pp = p + (size_t)node * HID + colb;
#pragma unroll
            for (int c = 0; c < 4; ++c) pp[c * 16] = acc[c][r];
        }
    }
}

// combine: p0+p1, +bias, relu, ns-scale, bf16 pack -> hs, f0b
__global__ __launch_bounds__(256) void k_gfin(const float* __restrict__ p0, const float* __restrict__ p1,
                                              const float* __restrict__ bin, const float* __restrict__ ns,
                                              unsigned int* __restrict__ hs, unsigned int* __restrict__ f0b) {
    int i = blockIdx.x * 256 + threadIdx.x;
    if (i >= NN * 16) return;
    int node = i >> 4;
    int q = i & 15;
    float4 a = ((const float4*)p0)[i];
    float4 b = ((const float4*)p1)[i];
    float4 bi = ((const float4*)bin)[q];
    float nsv = ns[node];
    float q0 = fmaxf(a.x + b.x + bi.x, 0.0f);
    float q1 = fmaxf(a.y + b.y + bi.y, 0.0f);
    float q2 = fmaxf(a.z + b.z + bi.z, 0.0f);
    float q3 = fmaxf(a.w + b.w + bi.w, 0.0f);
    uint2 pk;
    pk.x = f2bf(q0 * nsv) | (f2bf(q1 * nsv) << 16);
    pk.y = f2bf(q2 * nsv) | (f2bf(q3 * nsv) << 16);
    *(uint2*)(hs + (size_t)node * 32 + q * 2) = pk;
    uint2 pf;
    pf.x = f2bf(q0 * 0.1f) | (f2bf(q1 * 0.1f) << 16);
    pf.y = f2bf(q2 * 0.1f) | (f2bf(q3 * 0.1f) << 16);
    *(uint2*)(f0b + (size_t)node * 32 + q * 2) = pf;
}

// ---------------- fused layer: group-per-node agg (8 gathers in flight, col prefetch) + 8-wave matmul ----------------
__global__ __launch_bounds__(512) void k_layer(const unsigned int* __restrict__ hs_in, const int* __restrict__ col,
                                               const int* __restrict__ row_start, const int* __restrict__ din,
                                               const float* __restrict__ nd, const unsigned int* __restrict__ f0b,
                                               const float* __restrict__ w1p, const float* __restrict__ w2p,
                                               const float* __restrict__ bias, const float* __restrict__ ns,
                                               float* __restrict__ h, unsigned int* __restrict__ hs_out, int write_h) {
    __shared__ float fT[HID * PADN];
    __shared__ float f0T[HID * PADN];
    int tid = threadIdx.x;
    int lane = tid & 63;
    int wv = tid >> 6;   // 0..7
    int nb = blockIdx.x * 64;
    int g = lane >> 4;   // group 0..3 (one node each)
    int ql = lane & 15;  // lane within group: owns dims [4ql, 4ql+4)

    int nlP[2], baseP[2], degP[2], idxP[2];
    float ndP[2];
#pragma unroll
    for (int p = 0; p < 2; ++p) {
        int nl = wv * 8 + p * 4 + g;
        int n = min(nb + nl, NN - 1);
        nlP[p] = nl;
        baseP[p] = row_start[n];
        degP[p] = din[n];
        ndP[p] = nd[n];
    }
#pragma unroll
    for (int p = 0; p < 2; ++p) {
        idxP[p] = (ql < min(16, degP[p])) ? col[baseP[p] + ql] : 0;
    }

    for (int i = tid; i < 64 * 16; i += 512) {
        int nl = i >> 4;
        int q = i & 15;
        int n = min(nb + nl, NN - 1);
        uint2 v = *(const uint2*)(f0b + (size_t)n * 32 + q * 2);
        f0T[(q * 4 + 0) * PADN + nl] = bflo(v.x);
        f0T[(q * 4 + 1) * PADN + nl] = bfhi(v.x);
        f0T[(q * 4 + 2) * PADN + nl] = bflo(v.y);
        f0T[(q * 4 + 3) * PADN + nl] = bfhi(v.y);
    }

#pragma unroll
    for (int pass = 0; pass < 2; ++pass) {
        int base = baseP[pass];
        int deg = degP[pass];
        int idxv = idxP[pass];
        float ax = 0.0f, ay = 0.0f, az = 0.0f, aw = 0.0f;
        for (int done = 0; done < deg; done += 16) {
            int cnt = min(16, deg - done);
            int nxt = done + 16;
            int idxn = 0;
            if (nxt < deg && ql < deg - nxt) idxn = col[base + nxt + ql];
            uint2 pv[8];
#pragma unroll
            for (int e = 0; e < 8; ++e) {
                int s = __shfl(idxv, (g << 4) | e, 64);
                uint2 v = {0u, 0u};
                if (e < cnt) v = *(const uint2*)(hs_in + (size_t)s * 32 + ql * 2);
                pv[e] = v;
            }
#pragma unroll
            for (int e = 0; e < 8; ++e) {
                ax += bflo(pv[e].x);
                ay += bfhi(pv[e].x);
                az += bflo(pv[e].y);
                aw += bfhi(pv[e].y);
            }
#pragma unroll
            for (int e = 0; e < 8; ++e) {
                int s = __shfl(idxv, (g << 4) | (8 + e), 64);
                uint2 v = {0u, 0u};
                if (8 + e < cnt) v = *(const uint2*)(hs_in + (size_t)s * 32 + ql * 2);
                pv[e] = v;
            }
#pragma unroll
            for (int e = 0; e < 8; ++e) {
                ax += bflo(pv[e].x);
                ay += bfhi(pv[e].x);
                az += bflo(pv[e].y);
                aw += bfhi(pv[e].y);
            }
            idxv = idxn;
        }
        float sc = 0.9f * ndP[pass];
        int nl = nlP[pass];
        fT[(ql * 4 + 0) * PADN + nl] = ax * sc;
        fT[(ql * 4 + 1) * PADN + nl] = ay * sc;
        fT[(ql * 4 + 2) * PADN + nl] = az * sc;
        fT[(ql * 4 + 3) * PADN + nl] = aw * sc;
    }
    __syncthreads();

    int cg = __builtin_amdgcn_readfirstlane(wv) * 8;
    const float* w1b = w1p + cg;
    const float* w2b = w2p + cg;
    float acc[8];
#pragma unroll
    for (int c = 0; c < 8; c++) acc[c] = 0.0f;
    for (int k = 0; k < HID; ++k) {
        float fk = fT[k * PADN + lane];
        float f0k = f0T[k * PADN + lane];
        const float* w1r = w1b + (size_t)k * HID;
        const float* w2r = w2b + (size_t)k * HID;
#pragma unroll
        for (int c = 0; c < 8; c++) acc[c] += fk * w1r[c] + f0k * w2r[c];
    }
    int node = nb + lane;
    if (node < NN) {
        float nsv = ns[node];
        const float* bp = bias + cg;
        float q[8];
#pragma unroll
        for (int c = 0; c < 8; c++) q[c] = fmaxf(acc[c] + bp[c], 0.0f);
        uint2* hsp = (uint2*)(hs_out + (size_t)node * 32 + cg / 2);
#pragma unroll
        for (int c4 = 0; c4 < 2; c4++) {
            uint2 pk;
            pk.x = f2bf(q[c4 * 4 + 0] * nsv) | (f2bf(q[c4 * 4 + 1] * nsv) << 16);
            pk.y = f2bf(q[c4 * 4 + 2] * nsv) | (f2bf(q[c4 * 4 + 3] * nsv) << 16);
            hsp[c4] = pk;
        }
        if (write_h) {
            float4* hp = (float4*)(h + (size_t)node * HID + cg);
            float4 v0 = {q[0], q[1], q[2], q[3]};
            float4 v1 = {q[4], q[5], q[6], q[7]};
            hp[0] = v0;
            hp[1] = v1;
        }
    }
}

// ---------------- output: block = 128 nodes; wave pair splits the 40 cols; LDS lse reduce ----------------
__global__ __launch_bounds__(256) void k_out(const float* __restrict__ h, const float* __restrict__ Wout,
                                             const float* __restrict__ bout, float* __restrict__ out) {
    __shared__ float red_mx[4][64];
    __shared__ float red_s[4][64];
    int tid = threadIdx.x;
    int lane = tid & 63;
    int wv = tid >> 6;
    int half = wv & 1;
    int grp = wv >> 1;
    int node = blockIdx.x * 128 + grp * 64 + lane;
    int nodec = min(node, NN - 1);
    float acc[20];
#pragma unroll
    for (int c = 0; c < 20; c++) acc[c] = 0.0f;
    const float4* hr = (const float4*)(h + (size_t)nodec * HID);
    const float* wb = Wout + half * 20;
    for (int kk = 0; kk < HID / 4; ++kk) {
        float4 a = hr[kk];
        float av[4] = {a.x, a.y, a.z, a.w};
#pragma unroll
        for (int j = 0; j < 4; j++) {
            const float* wr = wb + (size_t)(kk * 4 + j) * OUTF;
#pragma unroll
            for (int c = 0; c < 20; c++) acc[c] += av[j] * wr[c];
        }
    }
    const float* bp = bout + half * 20;
#pragma unroll
    for (int c = 0; c < 20; c++) acc[c] += bp[c];
    float mx = acc[0];
#pragma unroll
    for (int c = 1; c < 20; c++) mx = fmaxf(mx, acc[c]);
    red_mx[wv][lane] = mx;
    __syncthreads();
    float gmx = fmaxf(mx, red_mx[wv ^ 1][lane]);
    float s = 0.0f;
#pragma unroll
    for (int c = 0; c < 20; c++) s += expf(acc[c] - gmx);
    red_s[wv][lane] = s;
    __syncthreads();
    float lse = logf(s + red_s[wv ^ 1][lane]) + gmx;
    if (node < NN) {
        float4* op = (float4*)(out + (size_t)node * OUTF + half * 20);
#pragma unroll
        for (int q = 0; q < 5; q++) {
            float4 v;
            v.x = acc[q * 4 + 0] - lse;
            v.y = acc[q * 4 + 1] - lse;
            v.z = acc[q * 4 + 2] - lse;
            v.w = acc[q * 4 + 3] - lse;
            op[q] = v;
        }
    }
}

extern "C" void kernel_launch(void* const* d_in, const int* in_sizes, int n_in,
                              void* d_out, int out_size, void* d_ws, size_t ws_size,
                              hipStream_t stream) {
    const float* feat = (const float*)d_in[0];
    const float* Win  = (const float*)d_in[1];
    const float* bin  = (const float*)d_in[2];
    const float* W1   = (const float*)d_in[3];
    const float* W2   = (const float*)d_in[4];
    const float* bvec = (const float*)d_in[5];
    const float* Wout = (const float*)d_in[6];
    const float* bout = (const float*)d_in[7];
    const int*   src  = (const int*)d_in[8];
    const int*   dst  = (const int*)d_in[9];
    float* out = (float*)d_out;

    char* ws = (char*)d_ws;
    size_t off = 0;
    auto take = [&](size_t bytes) {
        void* p = ws + off;
        off += (bytes + 255) & ~(size_t)255;
        return p;
    };
    int* din       = (int*)take(NN * 4);
    int* bsum      = (int*)take(256 * 4);
    int* row_start = (int*)take(NN * 4);
    int* col       = (int*)take(NE * 4);
    float* nsrc    = (float*)take(NN * 4);
    float* ndst    = (float*)take(NN * 4);
    int* cntD      = (int*)take(SLEN * 4);
    int* cntS      = (int*)take(SLEN * 4);
    int* offD      = (int*)take(SLEN * 4);
    int* offS      = (int*)take(SLEN * 4);
    int* sincl     = (int*)take(SLEN * 4);
    float* w1p     = (float*)take((size_t)NL * HID * HID * 4);
    float* w2p     = (float*)take((size_t)NL * HID * HID * 4);
    unsigned short* wfrag = (unsigned short*)take((size_t)INF * HID * 2);
    unsigned int* f0b = (unsigned int*)take((size_t)NN * HID * 2);  // bf16
    float* hbuf    = (float*)take((size_t)NN * HID * 4);            // gemm0 partial p0; edst alias
    float* part1   = (float*)take((size_t)NN * HID * 4);            // gemm0 partial p1; esrc alias
    unsigned int* hsA = (unsigned int*)take((size_t)NN * HID * 2);  // bf16
    unsigned int* hsB = (unsigned int*)take((size_t)NN * HID * 2);  // bf16

    // setup-phase aliases (dead before k_gemm0 writes them)
    uint2* edst = (uint2*)hbuf;   // NE * 8B = 6.4 MB <= 12.8 MB
    int* esrc   = (int*)part1;    // NE * 4B = 3.2 MB

    const int NB_W = (NN + 63) / 64;     // 782
    const int NB_O = (NN + 127) / 128;   // 391
    const int NB_S = SLEN / 256;         // 196

    // bucketed CSR build (zero global atomics)
    k_cnt<<<NBLK, 256, 0, stream>>>(src, dst, cntD, cntS);
    gscanA<<<NB_S, 256, 0, stream>>>(cntD, sincl, bsum, SLEN);
    gscanB<<<1, 256, 0, stream>>>(bsum, NB_S);
    gscanC<<<NB_S, 256, 0, stream>>>(sincl, cntD, bsum, offD, SLEN);
    gscanA<<<NB_S, 256, 0, stream>>>(cntS, sincl, bsum, SLEN);
    gscanB<<<1, 256, 0, stream>>>(bsum, NB_S);
    gscanC<<<NB_S, 256, 0, stream>>>(sincl, cntS, bsum, offS, SLEN);
    k_scat<<<NBLK, 256, 0, stream>>>(src, dst, offD, offS, edst, esrc);
    k_bcsr<<<NBUK, 256, 0, stream>>>(edst, offD, din, ndst, row_start, col);
    k_bns<<<NBUK, 256, 0, stream>>>(esrc, offS, nsrc);

    k_wprep<<<(NL * HID * HID + 255) / 256, 256, 0, stream>>>(W1, W2, w1p, w2p);
    k_wfrag<<<(INF * HID + 255) / 256, 256, 0, stream>>>(Win, wfrag);
    k_gemm0<<<2 * NB_W, 256, 0, stream>>>(feat, wfrag, hbuf, part1);
    k_gfin<<<(NN * 16 + 255) / 256, 256, 0, stream>>>(hbuf, part1, bin, nsrc, hsA, f0b);

    // ping-pong bf16 hs buffers (gathers read arbitrary rows; in-place would race)
    for (int l = 0; l < NL; ++l) {
        const unsigned int* hin = (l & 1) ? hsB : hsA;
        unsigned int* hout = (l & 1) ? hsA : hsB;
        k_layer<<<NB_W, 512, 0, stream>>>(hin, col, row_start, din, ndst, f0b,
                                          w1p + l * HID * HID, w2p + l * HID * HID,
                                          bvec + l * HID, nsrc, hbuf, hout, (l == NL - 1) ? 1 : 0);
    }
    k_out<<<NB_O, 256, 0, stream>>>(hbuf, Wout, bout, out);
}